// Round 1
// baseline (103.221 us; speedup 1.0000x reference)
//
#include <hip/hip_runtime.h>
#include <math.h>

// Problem constants (from reference setup_inputs)
#define NB 32
#define NA 5
#define NC 20
#define NH 64
#define NW 64
#define MAXB 50
#define CELLS_PER_BLOCK 1024      // 256 threads x 4 adjacent cells (float4)
#define BLOCKS_PER_BATCH 20       // 20480 / 1024
#define NBLK 640                  // NB * BLOCKS_PER_BATCH
#define OBJ_SCALE 5.0f
#define SILC 0.375f               // 0.6/(1+0.6): iou>0.6 <=> inter > SILC*(pa+ga)

__device__ __forceinline__ float fsig(float v) {
    return __builtin_amdgcn_rcpf(1.0f + __expf(-v));
}

__device__ __forceinline__ float iou_full(float x1, float y1, float w1, float h1,
                                          float x2, float y2, float w2, float h2) {
    float l = fmaxf(x1 - 0.5f * w1, x2 - 0.5f * w2);
    float r = fminf(x1 + 0.5f * w1, x2 + 0.5f * w2);
    float t = fmaxf(y1 - 0.5f * h1, y2 - 0.5f * h2);
    float b = fminf(y1 + 0.5f * h1, y2 + 0.5f * h2);
    float inter = fmaxf(r - l, 0.0f) * fmaxf(b - t, 0.0f);
    float uni = w1 * h1 + w2 * h2 - inter;
    return inter / fmaxf(uni, 1e-10f);
}

// Main kernel: per-block ballot compaction of GT boxes, sparse winner-cell
// corrections in wave 0 of blocks with rb==0, dense default-target loss for
// 4 ADJACENT cells/thread via float4 loads (5x dwordx4 instead of 10x dword:
// halves VMEM instruction count, 16B/lane coalescing sweet spot, and halves
// per-block fixed costs vs the 1280-block version). One PLAIN partial store
// per block (no atomics, no fences — R4's done-counter atomic cost ~25 us).
__global__ __launch_bounds__(256) void region_main(
        const float* __restrict__ out, const float* __restrict__ target,
        const float* __restrict__ anchors, float* __restrict__ ws) {
    __shared__ float s_t[MAXB * 5];
    __shared__ float s_box[250];    // bl[50] br[50] bt[50] bb[50] thr[50]
    __shared__ int s_flat[64];
    __shared__ int s_nv;
    __shared__ float s_p[4];

    const int tid = threadIdx.x;
    const int blk = blockIdx.x;
    const int b = blk / BLOCKS_PER_BATCH;
    const int rb = blk - b * BLOCKS_PER_BATCH;

    // ---- issue the dense loads FIRST (longest latency, independent) ----
    const int a = rb >> 2;                    // anchor idx, uniform per block
    const int ji0 = (rb & 3) << 10;           // within-anchor-plane cell offset
    const float* obase = out + ((size_t)(b * 125 + a * 25) << 12);
    const float4* p4 = (const float4*)(obase + ji0) + tid;   // 16B aligned
    float4 xr = p4[0];                        // plane stride = 4096 floats = 1024 float4
    float4 yr = p4[1024];
    float4 wr = p4[2048];
    float4 hr = p4[3072];
    float4 cr = p4[4096];

    // coalesced load of this batch's target slab (L2-hot after first touch)
    const float* tg = target + b * MAXB * 5;
    if (tid < 250) s_t[tid] = tg[tid];
    __syncthreads();

    float v = 0.0f;   // this thread's loss contribution

    if (tid < 64) {   // wave 0: compaction (+ sparse for rb==0)
        bool valid = false;
        float gx = 0, gy = 0, gw = 0, gh = 0, clsf = 0;
        if (tid < MAXB) {
            clsf = s_t[tid * 5 + 0];
            float xx = s_t[tid * 5 + 1];
            gx = xx * 64.0f;
            gy = s_t[tid * 5 + 2] * 64.0f;
            gw = s_t[tid * 5 + 3] * 64.0f;
            gh = s_t[tid * 5 + 4] * 64.0f;
            valid = xx > 0.0f;
        }
        unsigned long long mask = __ballot(valid);
        int pos = __popcll(mask & ((1ull << tid) - 1ull));
        int nv = __popcll(mask);
        if (valid) {
            s_box[pos]       = gx - 0.5f * gw;
            s_box[50 + pos]  = gx + 0.5f * gw;
            s_box[100 + pos] = gy - 0.5f * gh;
            s_box[150 + pos] = gy + 0.5f * gh;
            s_box[200 + pos] = SILC * gw * gh;
        }
        if (tid == 0) s_nv = nv;

        if (rb == 0) {
            // sparse winner-cell corrections (one batch per 20 blocks)
            float aw_[NA], ah_[NA];
            for (int q = 0; q < NA; ++q) { aw_[q] = anchors[2 * q]; ah_[q] = anchors[2 * q + 1]; }
            int best_n = 0, gi = 0, gj = 0, myflat = -1;
            if (valid) {
                float besti = -1.0f;
                for (int q = 0; q < NA; ++q) {          // first-max like jnp.argmax
                    float inter = fminf(gw, aw_[q]) * fminf(gh, ah_[q]);
                    float iou = inter / fmaxf(gw * gh + aw_[q] * ah_[q] - inter, 1e-10f);
                    if (iou > besti) { besti = iou; best_n = q; }
                }
                gi = min(max((int)floorf(gx), 0), 63);
                gj = min(max((int)floorf(gy), 0), 63);
                myflat = (best_n << 12) | (gj << 6) | gi;
            }
            s_flat[tid] = myflat;   // wave-synchronous: visible within wave 0

            // last-write-wins: winner iff no higher-index box maps to same cell
            bool winner = (myflat >= 0);
            if (winner) {
                for (int t2 = tid + 1; t2 < MAXB; ++t2)
                    if (s_flat[t2] == myflat) { winner = false; break; }
            }
            if (winner) {
                const float* basep = out + ((size_t)(b * 125 + best_n * 25) << 12)
                                   + (gj << 6) + gi;
                float xrw = basep[0];
                float yrw = basep[1 * 4096];
                float wrw = basep[2 * 4096];
                float hrw = basep[3 * 4096];
                float crw = basep[4 * 4096];

                float x = fsig(xrw), y = fsig(yrw), conf = fsig(crw);
                float aw = aw_[best_n], ah = ah_[best_n];
                float pw = __expf(wrw) * aw, ph = __expf(hrw) * ah;
                float px = x + (float)gi, py = y + (float)gj;
                float pl = px - 0.5f * pw, pr2 = px + 0.5f * pw;
                float pt = py - 0.5f * ph, pb2 = py + 0.5f * ph;
                float pa375 = SILC * (pw * ph);

                bool hit = false;
                for (int k = 0; k < nv; ++k) {
                    float l = fmaxf(pl, s_box[k]);
                    float r = fminf(pr2, s_box[50 + k]);
                    float t = fmaxf(pt, s_box[100 + k]);
                    float bo = fminf(pb2, s_box[150 + k]);
                    float inter = fmaxf(r - l, 0.0f) * fmaxf(bo - t, 0.0f);
                    hit = hit || (inter > pa375 + s_box[200 + k]);
                }
                float cb = hit ? 0.0f : 1.0f;

                float txv = gx - (float)gi;
                float tyv = gy - (float)gj;
                float twv = __logf(fmaxf(gw, 1e-10f) / aw);
                float thv = __logf(fmaxf(gh, 1e-10f) / ah);
                float tconf = iou_full(gx, gy, gw, gh, px, py, pw, ph);

                float dxn = x - txv, dyn = y - tyv, dwn = wrw - twv, dhn = hrw - thv;
                float dxo = x - 0.5f, dyo = y - 0.5f;
                float dc = conf - tconf;

                v += 0.5f * ((dxn * dxn - dxo * dxo) + (dyn * dyn - dyo * dyo)
                           + (dwn * dwn - wrw * wrw) + (dhn * dhn - hrw * hrw))
                   + 0.5f * (OBJ_SCALE * dc * dc - cb * conf * conf);

                // class NLL: -log_softmax(logits)[cls]
                const float* cl = basep + 5 * 4096;
                float lg[NC];
                float m = -INFINITY;
                for (int c = 0; c < NC; ++c) { lg[c] = cl[c * 4096]; m = fmaxf(m, lg[c]); }
                float s = 0.0f;
                for (int c = 0; c < NC; ++c) s += __expf(lg[c] - m);
                int ci = (int)clsf;
                v -= (lg[ci] - m - __logf(s));
            }
        }
    }
    __syncthreads();

    // ---- dense pass: 4 adjacent cells/thread, box data shared per k-iter ----
    const float aw = anchors[2 * a], ah = anchors[2 * a + 1];
    const int nv = s_nv;

    const int cell0 = ji0 + (tid << 2);
    const int i0 = cell0 & 63;           // cells 0..3 share a row (i0 % 4 == 0)
    const float fj = (float)(cell0 >> 6);

    float xs[4] = {xr.x, xr.y, xr.z, xr.w};
    float ys[4] = {yr.x, yr.y, yr.z, yr.w};
    float wsr[4] = {wr.x, wr.y, wr.z, wr.w};
    float hsr[4] = {hr.x, hr.y, hr.z, hr.w};
    float cs[4] = {cr.x, cr.y, cr.z, cr.w};

    float pl[4], pr[4], pt[4], pb[4], pa[4], cf[4];
    #pragma unroll
    for (int k = 0; k < 4; ++k) {
        float x = fsig(xs[k]);
        float y = fsig(ys[k]);
        cf[k] = fsig(cs[k]);
        float pw = __expf(wsr[k]) * aw;
        float ph = __expf(hsr[k]) * ah;
        float px = x + (float)(i0 + k);
        float py = y + fj;
        pl[k] = px - 0.5f * pw;  pr[k] = px + 0.5f * pw;
        pt[k] = py - 0.5f * ph;  pb[k] = py + 0.5f * ph;
        pa[k] = SILC * (pw * ph);
        float dx = x - 0.5f, dy = y - 0.5f;
        v += 0.5f * (dx * dx + dy * dy + wsr[k] * wsr[k] + hsr[k] * hsr[k]);
    }

    bool hit[4] = {false, false, false, false};
    for (int kk = 0; kk < nv; ++kk) {
        float bl = s_box[kk];
        float br = s_box[50 + kk];
        float bt = s_box[100 + kk];
        float bb = s_box[150 + kk];
        float th = s_box[200 + kk];
        #pragma unroll
        for (int k = 0; k < 4; ++k) {
            float in0 = fmaxf(fminf(pr[k], br) - fmaxf(pl[k], bl), 0.0f)
                      * fmaxf(fminf(pb[k], bb) - fmaxf(pt[k], bt), 0.0f);
            hit[k] = hit[k] || (in0 > pa[k] + th);
        }
    }
    #pragma unroll
    for (int k = 0; k < 4; ++k)
        v += hit[k] ? 0.0f : 0.5f * cf[k] * cf[k];

    // ---- block reduce -> one plain store ----
    for (int off = 32; off; off >>= 1) v += __shfl_down(v, off);
    if ((tid & 63) == 0) s_p[tid >> 6] = v;
    __syncthreads();
    if (tid == 0)
        ws[blk] = s_p[0] + s_p[1] + s_p[2] + s_p[3];
}

// Final reduction: sum NBLK partials -> loss[0]
__global__ __launch_bounds__(256) void region_reduce(
        const float* __restrict__ ws, float* __restrict__ loss) {
    __shared__ float s_p[4];
    const int tid = threadIdx.x;
    float v = 0.0f;
    for (int idx = tid; idx < NBLK; idx += 256) v += ws[idx];
    for (int off = 32; off; off >>= 1) v += __shfl_down(v, off);
    if ((tid & 63) == 0) s_p[tid >> 6] = v;
    __syncthreads();
    if (tid == 0) loss[0] = s_p[0] + s_p[1] + s_p[2] + s_p[3];
}

extern "C" void kernel_launch(void* const* d_in, const int* in_sizes, int n_in,
                              void* d_out, int out_size, void* d_ws, size_t ws_size,
                              hipStream_t stream) {
    (void)in_sizes; (void)n_in; (void)ws_size; (void)out_size;
    const float* output  = (const float*)d_in[0];
    const float* target  = (const float*)d_in[1];
    const float* anchors = (const float*)d_in[2];
    float* ws = (float*)d_ws;
    float* loss = (float*)d_out;

    region_main<<<NBLK, 256, 0, stream>>>(output, target, anchors, ws);
    region_reduce<<<1, 256, 0, stream>>>(ws, loss);
}